// Round 4
// baseline (199.172 us; speedup 1.0000x reference)
//
#include <hip/hip_runtime.h>
#include <math.h>

#define NFFT  4096
#define MHALF 2048   // complex FFT size (N/2)
#define HOPSZ 1024
#define LX    441000
#define NB    32
#define NF    431
#define NK    2049
#define NWG   (NB * NF)   // 13792
#define CHUNK (NWG / 8)   // 1724, exact

// LDS index swizzle: XOR bits 7..4 into 3..0. Bijective on [0,2048).
#define SW(A) ((A) ^ (((A) >> 4) & 0xF))

__device__ __forceinline__ float2 cadd(float2 a, float2 b){ return make_float2(a.x+b.x, a.y+b.y); }
__device__ __forceinline__ float2 csub(float2 a, float2 b){ return make_float2(a.x-b.x, a.y-b.y); }
__device__ __forceinline__ float2 cmul(float2 a, float2 b){
  return make_float2(fmaf(a.x, b.x, -(a.y*b.y)), fmaf(a.x, b.y, a.y*b.x));
}

// ws layout (floats): [0,4096) window*scale | [4096,6144) exp(-2pi i t/2048), t<1024
//                     | [6144,10242) exp(-2pi i k/4096), k<=2048
__global__ void stft_init(float* __restrict__ ws) {
  int i = blockIdx.x * blockDim.x + threadIdx.x;
  const double PI = 3.14159265358979323846;
  if (i < 4096) {
    double w = 0.5 * (1.0 - cos(2.0 * PI * (double)i / 4096.0)) * (1.0 / 64.0);
    ws[i] = (float)w;
  }
  if (i < 1024) {
    double a = -2.0 * PI * (double)i / 2048.0;
    ws[4096 + 2 * i]     = (float)cos(a);
    ws[4096 + 2 * i + 1] = (float)sin(a);
  }
  if (i < 2049) {
    double a = -2.0 * PI * (double)i / 4096.0;
    ws[6144 + 2 * i]     = (float)cos(a);
    ws[6144 + 2 * i + 1] = (float)sin(a);
  }
}

// Radix-8 Stockham DIF butterfly j (span S), inputs a[0..7] already in regs,
// results written (twiddled) to X. N=2048 complex.
template<int S>
__device__ __forceinline__ void bf8(float2* __restrict__ X,
                                    const float2* __restrict__ twg,
                                    int j, const float2* a) {
  const int q = j & (S - 1);
  const int t = j - q;
  float2 t0 = cadd(a[0], a[4]), t1 = csub(a[0], a[4]);
  float2 t2 = cadd(a[2], a[6]), t3 = csub(a[2], a[6]);
  float2 t4 = cadd(a[1], a[5]), t5 = csub(a[1], a[5]);
  float2 t6 = cadd(a[3], a[7]), t7 = csub(a[3], a[7]);

  const float K = 0.70710678118654752f;
  float2 wt5  = make_float2(K * (t5.x + t5.y), K * (t5.y - t5.x));   // W8   * t5
  float2 w3t7 = make_float2(K * (t7.y - t7.x), -K * (t7.x + t7.y));  // W8^3 * t7
  float2 wt7  = make_float2(K * (t7.x + t7.y), K * (t7.y - t7.x));   // W8   * t7
  float2 w3t5 = make_float2(K * (t5.y - t5.x), -K * (t5.x + t5.y));  // W8^3 * t5

  float2 e0 = cadd(t0, t2), e1 = csub(t0, t2);
  float2 f0 = cadd(t4, t6), f1 = csub(t4, t6);
  float2 B0 = cadd(e0, f0);
  float2 B4 = csub(e0, f0);
  float2 B2 = make_float2(e1.x + f1.y, e1.y - f1.x);
  float2 B6 = make_float2(e1.x - f1.y, e1.y + f1.x);
  float2 g0 = make_float2(t1.x + t3.y, t1.y - t3.x);
  float2 g1 = make_float2(t1.x - t3.y, t1.y + t3.x);
  float2 h0 = cadd(wt5, w3t7);
  float2 h1 = cadd(wt7, w3t5);
  float2 B1 = cadd(g0, h0);
  float2 B5 = csub(g0, h0);
  float2 B3 = cadd(g1, h1);
  float2 B7 = csub(g1, h1);

  float2 w1 = twg[t];          // exp(-2pi i t/2048)
  float2 w2 = cmul(w1, w1);
  float2 w3 = cmul(w2, w1);
  float2 w4 = cmul(w2, w2);
  float2 w5 = cmul(w3, w2);
  float2 w6 = cmul(w3, w3);
  float2 w7 = cmul(w4, w3);

  const int o = q + 8 * t;
  X[SW(o)]         = B0;
  X[SW(o + S)]     = cmul(w1, B1);
  X[SW(o + 2 * S)] = cmul(w2, B2);
  X[SW(o + 3 * S)] = cmul(w3, B3);
  X[SW(o + 4 * S)] = cmul(w4, B4);
  X[SW(o + 5 * S)] = cmul(w5, B5);
  X[SW(o + 6 * S)] = cmul(w6, B6);
  X[SW(o + 7 * S)] = cmul(w7, B7);
}

// One wave (64 threads) = one workgroup = one frame. All __syncthreads are
// single-wave (compile to the lgkmcnt waits we need anyway) -> zero cross-wave
// serialization; 10 independent waves/CU (LDS-limited: 16 KB each).
__global__ __launch_bounds__(64) void stft_fft(const float* __restrict__ x,
                                               const float* __restrict__ ws,
                                               float* __restrict__ out) {
  __shared__ float2 fbuf[2048];   // 16 KB, SW-swizzled workspace

  const int tid = threadIdx.x;    // 0..63
  const int wid = (blockIdx.x & 7) * CHUNK + (blockIdx.x >> 3);
  const int b = wid / NF;
  const int f = wid - b * NF;

  const float*  win  = ws;
  const float2* winv = (const float2*)ws;
  const float2* twg  = (const float2*)(ws + 4096);
  const float2* tw4  = (const float2*)(ws + 6144);
  const float* xb = x + (size_t)b * LX;
  const int base = f * HOPSZ - MHALF;

  // ---- load + window + radix-8 stage 1 (S=1), fused: global -> regs -> LDS
  float2 a[4][8];
  if (base >= 0 && base + NFFT <= LX) {
    const float2* xv = (const float2*)(xb + base);  // base even -> aligned
#pragma unroll
    for (int r = 0; r < 4; ++r) {
      const int j = tid + (r << 6);
#pragma unroll
      for (int m = 0; m < 8; ++m) {
        const int idx = j + (m << 8);
        float2 v = xv[idx];
        float2 w = winv[idx];
        a[r][m] = make_float2(v.x * w.x, v.y * w.y);
      }
    }
  } else {  // edge frames (f in {0,1,429,430}): per-element reflect
#pragma unroll
    for (int r = 0; r < 4; ++r) {
      const int j = tid + (r << 6);
#pragma unroll
      for (int m = 0; m < 8; ++m) {
        const int idx = j + (m << 8);
        int s0 = base + 2 * idx;
        int s1 = s0 + 1;
        s0 = (s0 < 0) ? -s0 : ((s0 >= LX) ? (2 * LX - 2 - s0) : s0);
        s1 = (s1 < 0) ? -s1 : ((s1 >= LX) ? (2 * LX - 2 - s1) : s1);
        a[r][m] = make_float2(xb[s0] * win[2 * idx], xb[s1] * win[2 * idx + 1]);
      }
    }
  }
#pragma unroll
  for (int r = 0; r < 4; ++r) bf8<1>(fbuf, twg, tid + (r << 6), a[r]);
  __syncthreads();

  // ---- radix-8 stage 2 (S=8), in-place: read-all -> sync -> write-all
#pragma unroll
  for (int r = 0; r < 4; ++r) {
    const int j = tid + (r << 6);
#pragma unroll
    for (int m = 0; m < 8; ++m) a[r][m] = fbuf[SW(j + (m << 8))];
  }
  __syncthreads();
#pragma unroll
  for (int r = 0; r < 4; ++r) bf8<8>(fbuf, twg, tid + (r << 6), a[r]);
  __syncthreads();

  // ---- radix-8 stage 3 (S=64)
#pragma unroll
  for (int r = 0; r < 4; ++r) {
    const int j = tid + (r << 6);
#pragma unroll
    for (int m = 0; m < 8; ++m) a[r][m] = fbuf[SW(j + (m << 8))];
  }
  __syncthreads();
#pragma unroll
  for (int r = 0; r < 4; ++r) bf8<64>(fbuf, twg, tid + (r << 6), a[r]);
  __syncthreads();

  // ---- radix-4 stage 4 (S=512, twiddle-free), in-place
  float2 c[8][4];
#pragma unroll
  for (int r = 0; r < 8; ++r) {
    const int j = tid + (r << 6);
#pragma unroll
    for (int m = 0; m < 4; ++m) c[r][m] = fbuf[SW(j + (m << 9))];
  }
  __syncthreads();
#pragma unroll
  for (int r = 0; r < 8; ++r) {
    const int j = tid + (r << 6);
    float2 e0 = cadd(c[r][0], c[r][2]), e1 = csub(c[r][0], c[r][2]);
    float2 o0 = cadd(c[r][1], c[r][3]), o1 = csub(c[r][1], c[r][3]);
    fbuf[SW(j)]        = cadd(e0, o0);
    fbuf[SW(j + 512)]  = make_float2(e1.x + o1.y, e1.y - o1.x);  // e1 - i*o1
    fbuf[SW(j + 1024)] = csub(e0, o0);
    fbuf[SW(j + 1536)] = make_float2(e1.x - o1.y, e1.y + o1.x);  // e1 + i*o1
  }
  __syncthreads();

  // ---- real-FFT recombination (uniform formula, valid all k) + store
  float2* __restrict__ op = (float2*)out;
  const size_t ob = (size_t)b * NK * NF + f;
  float2 z0save = make_float2(0.f, 0.f);
#pragma unroll 4
  for (int it = 0; it < 32; ++it) {
    const int k  = tid + (it << 6);           // 0..2047
    const int km = (2048 - k) & 2047;
    float2 zk = fbuf[SW(k)];
    float2 zm = fbuf[SW(km)];
    if (k == 0) z0save = zk;
    float xex = 0.5f * (zk.x + zm.x);
    float xey = 0.5f * (zk.y - zm.y);
    float xox = 0.5f * (zk.y + zm.y);
    float xoy = 0.5f * (zm.x - zk.x);
    float2 w = tw4[k];
    float tx = w.x * xox - w.y * xoy;
    float ty = w.x * xoy + w.y * xox;
    op[ob + (size_t)k * NF] = make_float2(xex + tx, xey + ty);
  }
  if (tid == 0) {  // k = 2048 (Nyquist of the 4096-pt rfft)
    op[ob + (size_t)2048 * NF] = make_float2(z0save.x - z0save.y, 0.0f);
  }
}

extern "C" void kernel_launch(void* const* d_in, const int* in_sizes, int n_in,
                              void* d_out, int out_size, void* d_ws, size_t ws_size,
                              hipStream_t stream) {
  const float* x = (const float*)d_in[0];
  float* ws = (float*)d_ws;     // needs 10242 floats (~41 KB)
  float* out = (float*)d_out;
  stft_init<<<16, 256, 0, stream>>>(ws);
  stft_fft<<<NWG, 64, 0, stream>>>(x, ws, out);
}